// Round 13
// baseline (142.039 us; speedup 1.0000x reference)
//
#include <hip/hip_runtime.h>

// Problem constants: B=8, N_IN=256, N=8192, D=64, K=512
#define NIN    256
#define NCOL   8192
#define DDIM   64
#define KCODES 512
#define ZQ_ELEMS (8ull * 64ull * 8192ull)    // zq floats; hist follows

// ---------------------------------------------------------------------------
// K1 prep: Wt[i][d] = W[d][i] (conv s_loads contiguous); embT[d][k] =
// emb[k][d] (search s_loads contiguous in k); emb_sq[k] = ||emb[k]||^2
// (ascending-d, bit-exact vs all passing rounds); hist_out = ind_hist.
// ---------------------------------------------------------------------------
__global__ __launch_bounds__(256) void vq_prep(const float* __restrict__ W,
                                               const float* __restrict__ emb,
                                               const float* __restrict__ ind_hist,
                                               float* __restrict__ Wt,
                                               float* __restrict__ embT,
                                               float* __restrict__ emb_sq,
                                               float* __restrict__ hist_out)
{
    const int t = blockIdx.x * 256 + threadIdx.x;   // t < 32768
    if (t < NIN * DDIM) {
        int i = t >> 6;
        int d = t & 63;
        Wt[t] = W[d * NIN + i];
    }
    {
        int d = t >> 9;          // 0..63
        int k = t & 511;         // 0..511
        embT[t] = emb[k * DDIM + d];
    }
    if (t < KCODES) {
        const float* __restrict__ ek = emb + t * DDIM;
        float s = 0.f;
        #pragma unroll
        for (int d = 0; d < DDIM; ++d) s = fmaf(ek[d], ek[d], s);
        emb_sq[t] = s;
        hist_out[t] = ind_hist[t];
    }
}

// ---------------------------------------------------------------------------
// K2 conv: 1024 blocks x 512 thr / 8 waves, (512,8) -> cap 64 VGPR.
// Conv live set ~30 regs (acc[8]) — fits cap 64 (round 9's spill came from
// the search acc, not conv). 4 blocks/CU x 8 waves = 32 waves/CU = 8/SIMD:
// max latency hiding for this HBM-bound phase (z = 64 MB, floor ~10 us).
// Wave w -> d-slice [8w,8w+8) for 64 cols (lane=col, Wt s_load, ascending-i
// fmaf — bit-identical ze vs all passing rounds). Writes ze to OUTPUT buffer
// in (b,d,n) layout, coalesced; vq_searchfinal overwrites with zq.
// ---------------------------------------------------------------------------
__global__ __launch_bounds__(512, 8) void vq_conv(const float* __restrict__ z,
                                                  const float* __restrict__ Wt,
                                                  float* __restrict__ out)
{
    const int tid = threadIdx.x;
    const int cl  = tid & 63;
    const int w   = __builtin_amdgcn_readfirstlane(tid >> 6);   // 0..7
    const int C   = blockIdx.x * 64 + cl;
    const int b   = C >> 13;
    const int n   = C & (NCOL - 1);

    const float* __restrict__ zp = z + (size_t)b * NIN * NCOL + n;
    const float* __restrict__ wp = Wt + w * 8;

    float acc[8];
    #pragma unroll
    for (int j = 0; j < 8; ++j) acc[j] = 0.f;

    for (int i = 0; i < NIN; i += 4) {
        float z0 = zp[(size_t)(i + 0) * NCOL];
        float z1 = zp[(size_t)(i + 1) * NCOL];
        float z2 = zp[(size_t)(i + 2) * NCOL];
        float z3 = zp[(size_t)(i + 3) * NCOL];
        const float* __restrict__ w0 = wp + (size_t)(i + 0) * DDIM;  // s_load
        const float* __restrict__ w1 = wp + (size_t)(i + 1) * DDIM;
        const float* __restrict__ w2 = wp + (size_t)(i + 2) * DDIM;
        const float* __restrict__ w3 = wp + (size_t)(i + 3) * DDIM;
        #pragma unroll
        for (int j = 0; j < 8; ++j) {
            float a = acc[j];
            a = fmaf(w0[j], z0, a);   // ascending i: bit-exact
            a = fmaf(w1[j], z1, a);
            a = fmaf(w2[j], z2, a);
            a = fmaf(w3[j], z3, a);
            acc[j] = a;
        }
    }

    float* __restrict__ op = out + ((size_t)b * DDIM + w * 8) * NCOL + n;
    #pragma unroll
    for (int j = 0; j < 8; ++j) op[(size_t)j * NCOL] = acc[j];
}

// ---------------------------------------------------------------------------
// K3 search+final: 1024 blocks x 256 thr, (256,4) -> cap 128 VGPR.
//  stage  : coop-load ze tile (b,d,n) -> LDS transpose (round-11 verified).
//  pin    : each thread loads its column's FULL ze[64] with STATIC indices
//           (rule #20: runtime idx -> scratch, round 7's 165 MB FETCH) and
//           PINS each value with an empty asm (round 12: without the pin the
//           allocator remats the LDS reads into the k-loop -> mixed ds+smem
//           lgkm queue -> full-drain stalls; that is the 2.5x-over-floor
//           ceiling shared by rounds 3/4/6/8/11/12). Pinned values cannot be
//           rematerialized through the asm barrier.
//  search : wave w owns k-quarter [128w,128w+128), 8 rolled tiles of 16.
//           Per tile: fully-unrolled 64 j-steps: {wave-uniform s_load of
//           embT[j][kt..kt+16) -> 16 reg-reg v_fmac}. ZERO LDS, ZERO VMEM
//           in the hot loop; lgkm queue is SMEM-only -> counted waits.
//           dist = (zesq + emb_sq[k]) - 2*cr, ascending-d cr: bit-exact.
//  merge  : 4 per-wave candidates via LDS, ascending-w strict-< scan
//           == jnp.argmin first-min tie-break (round-12 verified).
//  epilog : wave w writes zq d-slice [16w,16w+16) from ze_lds (static idx);
//           1 hist atomic per column (round-12 verified).
// ---------------------------------------------------------------------------
__global__ __launch_bounds__(256, 4) void vq_searchfinal(
        const float* __restrict__ zeb,
        const float* __restrict__ emb,
        const float* __restrict__ embT,
        const float* __restrict__ emb_sq,
        float* __restrict__ out,
        float* __restrict__ hist)
{
    __shared__ float ze_lds[64][DDIM + 1];   // stride 65: b32 conflict-free
    __shared__ float bw_lds[4][64];
    __shared__ int   bk_lds[4][64];

    const int tid = threadIdx.x;
    const int C0  = blockIdx.x * 64;
    const int b   = C0 >> 13;                // 64-col tile never crosses b
    const int n0  = C0 & (NCOL - 1);

    // ---- coop load ze tile from conv output (verified round-11 pattern) ---
    {
        const int r  = tid >> 2;
        const int cc = (tid & 3) * 16;
        const float4* __restrict__ src = reinterpret_cast<const float4*>(
            zeb + ((size_t)b * DDIM + r) * NCOL + n0 + cc);
        #pragma unroll
        for (int v = 0; v < 4; ++v) {
            float4 x = src[v];
            ze_lds[cc + 4 * v + 0][r] = x.x;
            ze_lds[cc + 4 * v + 1][r] = x.y;
            ze_lds[cc + 4 * v + 2][r] = x.z;
            ze_lds[cc + 4 * v + 3][r] = x.w;
        }
    }
    __syncthreads();

    const int cl = tid & 63;
    const int w  = __builtin_amdgcn_readfirstlane(tid >> 6);    // 0..3

    // ---- ze -> registers: static indices + asm pin (no remat, no scratch) -
    float ze[DDIM];
    #pragma unroll
    for (int j = 0; j < DDIM; ++j) ze[j] = ze_lds[cl][j];
    #pragma unroll
    for (int j = 0; j < DDIM; ++j) asm volatile("" : "+v"(ze[j]));

    // ---- zesq: ascending-d chain (bit-exact) ------------------------------
    float zesq = 0.f;
    #pragma unroll
    for (int d = 0; d < DDIM; ++d) zesq = fmaf(ze[d], ze[d], zesq);

    // ---- search: wave w owns k in [128w, 128w+128) ------------------------
    const int k0 = __builtin_amdgcn_readfirstlane(w * (KCODES / 4));
    float best  = 3.4e38f;
    int   bestk = k0;

    #pragma unroll 1
    for (int t8 = 0; t8 < 8; ++t8) {                  // 8 rolled tiles of 16
        const int kt = k0 + t8 * 16;
        const float* __restrict__ ep0 = embT + kt;    // wave-uniform base

        float acc[16];
        #pragma unroll
        for (int kk = 0; kk < 16; ++kk) acc[kk] = 0.f;

        #pragma unroll
        for (int j = 0; j < DDIM; ++j) {              // fully static
            const float* __restrict__ ep = ep0 + (size_t)j * KCODES;  // s_load
            const float zj = ze[j];                   // pinned VGPR
            #pragma unroll
            for (int kk = 0; kk < 16; ++kk)
                acc[kk] = fmaf(ep[kk], zj, acc[kk]);  // ascending d per (c,k)
        }

        #pragma unroll
        for (int kk = 0; kk < 16; ++kk) {
            const int k = kt + kk;
            float dist = (zesq + emb_sq[k]) - 2.0f * acc[kk];  // ref order
            if (dist < best) { best = dist; bestk = k; }       // first-min
        }
    }
    bw_lds[w][cl] = best;
    bk_lds[w][cl] = bestk;
    __syncthreads();

    // ---- merge 4 candidates (ascending w, strict <) -----------------------
    float fb = bw_lds[0][cl];
    int   fk = bk_lds[0][cl];
    #pragma unroll
    for (int ww = 1; ww < 4; ++ww) {
        float v = bw_lds[ww][cl];
        int  kv = bk_lds[ww][cl];
        if (v < fb) { fb = v; fk = kv; }
    }

    // ---- histogram: one atomic per column ---------------------------------
    if (w == 0) atomicAdd(hist + fk, 1.0f);

    // ---- straight-through output: wave w writes d-slice [16w,16w+16) ------
    const int n = n0 + cl;
    const float4* __restrict__ eb =
        reinterpret_cast<const float4*>(emb + (size_t)fk * DDIM) + w * 4;
    float* __restrict__ op = out + ((size_t)b * DDIM + w * 16) * NCOL + n;
    #pragma unroll
    for (int v = 0; v < 4; ++v) {
        float4 e = eb[v];
        float z0 = ze_lds[cl][w * 16 + 4 * v + 0];   // LDS: static indices
        float z1 = ze_lds[cl][w * 16 + 4 * v + 1];
        float z2 = ze_lds[cl][w * 16 + 4 * v + 2];
        float z3 = ze_lds[cl][w * 16 + 4 * v + 3];
        op[(size_t)(4 * v + 0) * NCOL] = z0 + (e.x - z0);
        op[(size_t)(4 * v + 1) * NCOL] = z1 + (e.y - z1);
        op[(size_t)(4 * v + 2) * NCOL] = z2 + (e.z - z2);
        op[(size_t)(4 * v + 3) * NCOL] = z3 + (e.w - z3);
    }
}

// ---------------------------------------------------------------------------
extern "C" void kernel_launch(void* const* d_in, const int* in_sizes, int n_in,
                              void* d_out, int out_size, void* d_ws, size_t ws_size,
                              hipStream_t stream)
{
    const float* z        = (const float*)d_in[0];  // (8, 256, 8192)
    const float* W        = (const float*)d_in[1];  // (64, 256)
    const float* emb      = (const float*)d_in[2];  // (512, 64)
    const float* ind_hist = (const float*)d_in[3];  // (512,)

    float* out  = (float*)d_out;                    // zq then hist
    float* hist = out + ZQ_ELEMS;

    float* Wt     = (float*)d_ws;                   // 16384 floats
    float* embT   = Wt + NIN * DDIM;                // 32768 floats
    float* emb_sq = embT + DDIM * KCODES;           // 512 floats

    hipLaunchKernelGGL(vq_prep, dim3(128), dim3(256), 0, stream,
                       W, emb, ind_hist, Wt, embT, emb_sq, hist);

    // conv: 64 cols/block, 8 waves -> 32 waves/CU (HBM-latency phase)
    hipLaunchKernelGGL(vq_conv, dim3(1024), dim3(512), 0, stream,
                       z, Wt, out);

    // search+final: 64 cols/block, 4 waves, cap 128 (pinned ze ~100 VGPR)
    hipLaunchKernelGGL(vq_searchfinal, dim3(1024), dim3(256), 0, stream,
                       out, emb, embT, emb_sq, out, hist);
}